// Round 14
// baseline (130.324 us; speedup 1.0000x reference)
//
#include <hip/hip_runtime.h>

// Geometry (from reference): B=4, C=8, D=48, H=128, W=160
#define HW    20480      // H*W
#define DHW   983040     // D*H*W (channel stride, floats)
#define CDHW  7864320    // C*D*H*W (batch stride, floats)
#define NPIX  81920      // B*H*W
#define GPX   512        // pixels per block (256 thr x 2 px)
#define NGRP  40         // pixel groups per batch (HW / GPX)
#define DSTEP 8          // d-slices per chunk
#define NCHNK 6          // 48 / DSTEP
#define NBLK  (4 * NGRP * NCHNK)   // 960 blocks
#define EPS   1e-5f

typedef _Float16 half2v __attribute__((ext_vector_type(2)));

static __device__ __forceinline__ float dot2u(half2v a, unsigned wb, float c) {
#if __has_builtin(__builtin_amdgcn_fdot2)
    return __builtin_amdgcn_fdot2(a, __builtin_bit_cast(half2v, wb), c, false);
#else
    half2v b = __builtin_bit_cast(half2v, wb);
    return fmaf((float)a.x, (float)b.x, fmaf((float)a.y, (float)b.y, c));
#endif
}
static __device__ __forceinline__ half2v pk(float a, float b) {
#if __has_builtin(__builtin_amdgcn_cvt_pkrtz)
    return __builtin_bit_cast(half2v, __builtin_amdgcn_cvt_pkrtz(a, b));
#else
    half2v h; h.x = (_Float16)a; h.y = (_Float16)b; return h;
#endif
}
static __device__ __forceinline__ unsigned pku(float a, float b) {
    return __builtin_bit_cast(unsigned, pk(a, b));
}

// Each block = (batch, 512-px group, 8-slice d-chunk); 256 thr, 2 px/thread.
// x loaded global->register directly (coalesced float2 per channel) with
// depth-1 prefetch; weights live in LDS, read as wave-uniform broadcasts.
// NO __syncthreads in the main loop — latency hidden by 16 independent
// waves/CU instead of drained at barriers.
__global__ __launch_bounds__(256, 4)
void mlp_kernel(const float* __restrict__ x,
                const float* __restrict__ w0, const float* __restrict__ g0,
                const float* __restrict__ b0, const float* __restrict__ m0,
                const float* __restrict__ v0,
                const float* __restrict__ w1, const float* __restrict__ g1,
                const float* __restrict__ b1, const float* __restrict__ m1,
                const float* __restrict__ v1,
                const float* __restrict__ w2,
                float* __restrict__ ws)
{
    // LDS: only the f16-packed folded weights (~0.7 KB).
    __shared__ __align__(16) unsigned lw0u[64];   // [o][i] o<16 i<4 (ch pairs)
    __shared__ __align__(16) float    lb0[16];
    __shared__ __align__(16) unsigned lw1u[64];   // [j][i] j<8 i<8 (h0 pairs)
    __shared__ __align__(16) float    lb1[8];
    __shared__ __align__(16) unsigned lw2u[4];

    const int tid = threadIdx.x;

    // Task decode: 960 = 4 batches x 40 groups x 6 chunks.
    const int t     = blockIdx.x;
    const int batch = t / (NGRP * NCHNK);
    const int r     = t - batch * (NGRP * NCHNK);
    const int grp   = r / NCHNK;
    const int chunk = r - grp * NCHNK;

    // ---- per-block BN fold into LDS (f16 pairs) ----
    if (tid < 16) {
        float sc = g0[tid] * rsqrtf(v0[tid] + EPS);
#pragma unroll
        for (int i = 0; i < 4; ++i)
            lw0u[tid * 4 + i] = pku(w0[tid * 8 + 2 * i] * sc, w0[tid * 8 + 2 * i + 1] * sc);
        lb0[tid] = b0[tid] - m0[tid] * sc;
    } else if (tid < 24) {
        int j = tid - 16;
        float sc = g1[j] * rsqrtf(v1[j] + EPS);
#pragma unroll
        for (int i = 0; i < 8; ++i)
            lw1u[j * 8 + i] = pku(w1[j * 16 + 2 * i] * sc, w1[j * 16 + 2 * i + 1] * sc);
        lb1[j] = b1[j] - m1[j] * sc;
    } else if (tid == 24) {
#pragma unroll
        for (int i = 0; i < 4; ++i) lw2u[i] = pku(w2[2 * i], w2[2 * i + 1]);
    }
    __syncthreads();   // the ONLY barrier: weights ready

    // Pixel-pair base for this thread within its d-chunk.
    const float* xp = x + (size_t)batch * CDHW + (size_t)(chunk * DSTEP) * HW
                        + grp * GPX + tid * 2;

    float maxv0 = -1e30f, maxv1 = -1e30f;

    // Depth-1 register prefetch: cur holds slice dd, nxt is loading dd+1.
    float2 cur[8], nxt[8];
#pragma unroll
    for (int c = 0; c < 8; ++c) cur[c] = *(const float2*)(xp + (size_t)c * DHW);

    for (int dd = 0; dd < DSTEP; ++dd) {
        if (dd + 1 < DSTEP) {
            const float* xq = xp + (size_t)(dd + 1) * HW;
#pragma unroll
            for (int c = 0; c < 8; ++c) nxt[c] = *(const float2*)(xq + (size_t)c * DHW);
        }

        // ---- pack 2 px x 8 ch to f16 pairs ----
        half2v xh0[4], xh1[4];
#pragma unroll
        for (int i = 0; i < 4; ++i) {
            xh0[i] = pk(cur[2 * i].x, cur[2 * i + 1].x);
            xh1[i] = pk(cur[2 * i].y, cur[2 * i + 1].y);
        }

        // ---- layer 0: 8 -> 16, relu, pack pairs (both px) ----
        unsigned hh0[8], hh1[8];
#pragma unroll
        for (int op = 0; op < 8; ++op) {
            uint4 wA = *(const uint4*)&lw0u[(2 * op) * 4];
            uint4 wB = *(const uint4*)&lw0u[(2 * op + 1) * 4];
            float bA = lb0[2 * op], bB = lb0[2 * op + 1];
            float a0 = bA, c0 = bB, a1 = bA, c1 = bB;
            a0 = dot2u(xh0[0], wA.x, a0); a0 = dot2u(xh0[1], wA.y, a0);
            a0 = dot2u(xh0[2], wA.z, a0); a0 = dot2u(xh0[3], wA.w, a0);
            c0 = dot2u(xh0[0], wB.x, c0); c0 = dot2u(xh0[1], wB.y, c0);
            c0 = dot2u(xh0[2], wB.z, c0); c0 = dot2u(xh0[3], wB.w, c0);
            a1 = dot2u(xh1[0], wA.x, a1); a1 = dot2u(xh1[1], wA.y, a1);
            a1 = dot2u(xh1[2], wA.z, a1); a1 = dot2u(xh1[3], wA.w, a1);
            c1 = dot2u(xh1[0], wB.x, c1); c1 = dot2u(xh1[1], wB.y, c1);
            c1 = dot2u(xh1[2], wB.z, c1); c1 = dot2u(xh1[3], wB.w, c1);
            hh0[op] = pku(fmaxf(a0, 0.f), fmaxf(c0, 0.f));
            hh1[op] = pku(fmaxf(a1, 0.f), fmaxf(c1, 0.f));
        }

        // ---- layer 1: 16 -> 8, relu, pack pairs (explicit per-pixel) ----
        unsigned hq0[4], hq1[4];
#define L1PX(HH, HQ)                                                              \
        {                                                                         \
            float a = bA, b = bB;                                                 \
            a = dot2u(__builtin_bit_cast(half2v, HH[0]), wA0.x, a);               \
            a = dot2u(__builtin_bit_cast(half2v, HH[1]), wA0.y, a);               \
            a = dot2u(__builtin_bit_cast(half2v, HH[2]), wA0.z, a);               \
            a = dot2u(__builtin_bit_cast(half2v, HH[3]), wA0.w, a);               \
            a = dot2u(__builtin_bit_cast(half2v, HH[4]), wA1.x, a);               \
            a = dot2u(__builtin_bit_cast(half2v, HH[5]), wA1.y, a);               \
            a = dot2u(__builtin_bit_cast(half2v, HH[6]), wA1.z, a);               \
            a = dot2u(__builtin_bit_cast(half2v, HH[7]), wA1.w, a);               \
            b = dot2u(__builtin_bit_cast(half2v, HH[0]), wB0.x, b);               \
            b = dot2u(__builtin_bit_cast(half2v, HH[1]), wB0.y, b);               \
            b = dot2u(__builtin_bit_cast(half2v, HH[2]), wB0.z, b);               \
            b = dot2u(__builtin_bit_cast(half2v, HH[3]), wB0.w, b);               \
            b = dot2u(__builtin_bit_cast(half2v, HH[4]), wB1.x, b);               \
            b = dot2u(__builtin_bit_cast(half2v, HH[5]), wB1.y, b);               \
            b = dot2u(__builtin_bit_cast(half2v, HH[6]), wB1.z, b);               \
            b = dot2u(__builtin_bit_cast(half2v, HH[7]), wB1.w, b);               \
            HQ[jp] = pku(fmaxf(a, 0.f), fmaxf(b, 0.f));                           \
        }
#pragma unroll
        for (int jp = 0; jp < 4; ++jp) {
            uint4 wA0 = *(const uint4*)&lw1u[(2 * jp) * 8];
            uint4 wA1 = *(const uint4*)&lw1u[(2 * jp) * 8 + 4];
            uint4 wB0 = *(const uint4*)&lw1u[(2 * jp + 1) * 8];
            uint4 wB1 = *(const uint4*)&lw1u[(2 * jp + 1) * 8 + 4];
            float bA = lb1[2 * jp], bB = lb1[2 * jp + 1];
            L1PX(hh0, hq0)
            L1PX(hh1, hq1)
        }
#undef L1PX

        // ---- layer 2: 8 -> 1 (bias2 deferred), running max ----
        {
            uint4 w2v = *(const uint4*)&lw2u[0];
            float a0 = 0.f, a1 = 0.f;
            a0 = dot2u(__builtin_bit_cast(half2v, hq0[0]), w2v.x, a0);
            a0 = dot2u(__builtin_bit_cast(half2v, hq0[1]), w2v.y, a0);
            a0 = dot2u(__builtin_bit_cast(half2v, hq0[2]), w2v.z, a0);
            a0 = dot2u(__builtin_bit_cast(half2v, hq0[3]), w2v.w, a0);
            a1 = dot2u(__builtin_bit_cast(half2v, hq1[0]), w2v.x, a1);
            a1 = dot2u(__builtin_bit_cast(half2v, hq1[1]), w2v.y, a1);
            a1 = dot2u(__builtin_bit_cast(half2v, hq1[2]), w2v.z, a1);
            a1 = dot2u(__builtin_bit_cast(half2v, hq1[3]), w2v.w, a1);
            maxv0 = fmaxf(maxv0, a0);
            maxv1 = fmaxf(maxv1, a1);
        }

#pragma unroll
        for (int c = 0; c < 8; ++c) cur[c] = nxt[c];
    }

    // Plain store of this chunk's partial max.
    float2 st; st.x = maxv0; st.y = maxv1;
    *(float2*)&ws[(size_t)chunk * NPIX + (size_t)batch * HW + grp * GPX + tid * 2] = st;
}

// Reduce 6 chunk-partials, add bias2, sigmoid (monotone => commutes with max).
__global__ __launch_bounds__(256)
void finish_kernel(const float* __restrict__ ws, const float* __restrict__ bias2,
                   float* __restrict__ out)
{
    int i = blockIdx.x * 256 + threadIdx.x;
    float m = ws[i];
#pragma unroll
    for (int c = 1; c < NCHNK; ++c) m = fmaxf(m, ws[(size_t)c * NPIX + i]);
    m += bias2[0];
    out[i] = 1.0f / (1.0f + __expf(-m));
}

extern "C" void kernel_launch(void* const* d_in, const int* in_sizes, int n_in,
                              void* d_out, int out_size, void* d_ws, size_t ws_size,
                              hipStream_t stream) {
    const float* x1 = (const float*)d_in[0];
    float* ws = (float*)d_ws;   // needs 6 * 81920 * 4 = 2 MB

    mlp_kernel<<<NBLK, 256, 0, stream>>>(
        x1,
        (const float*)d_in[1], (const float*)d_in[2], (const float*)d_in[3],
        (const float*)d_in[4], (const float*)d_in[5],
        (const float*)d_in[6], (const float*)d_in[7], (const float*)d_in[8],
        (const float*)d_in[9], (const float*)d_in[10],
        (const float*)d_in[11],
        ws);
    finish_kernel<<<NPIX / 256, 256, 0, stream>>>(ws, (const float*)d_in[12],
                                                  (float*)d_out);
}

// Round 15
// 35.716 us; speedup vs baseline: 3.6489x; 3.6489x over previous
//
#include <hip/hip_runtime.h>

// Geometry (from reference): B=4, C=8, D=48, H=128, W=160
#define HW    20480      // H*W
#define DHW   983040     // D*H*W (channel stride, floats)
#define CDHW  7864320    // C*D*H*W (batch stride, floats)
#define NPIX  81920      // B*H*W
#define GPX   512        // pixels per block (256 thr x 2 px)
#define NGRP  40         // pixel groups per batch (HW / GPX)
#define DSTEP 8          // d-slices per chunk
#define NCHNK 6          // 48 / DSTEP
#define NBLK  (4 * NGRP * NCHNK)   // 960 blocks
#define EPS   1e-5f

typedef _Float16 half2v __attribute__((ext_vector_type(2)));

static __device__ __forceinline__ float dot2u(half2v a, unsigned wb, float c) {
#if __has_builtin(__builtin_amdgcn_fdot2)
    return __builtin_amdgcn_fdot2(a, __builtin_bit_cast(half2v, wb), c, false);
#else
    half2v b = __builtin_bit_cast(half2v, wb);
    return fmaf((float)a.x, (float)b.x, fmaf((float)a.y, (float)b.y, c));
#endif
}
static __device__ __forceinline__ half2v pk(float a, float b) {
#if __has_builtin(__builtin_amdgcn_cvt_pkrtz)
    return __builtin_bit_cast(half2v, __builtin_amdgcn_cvt_pkrtz(a, b));
#else
    half2v h; h.x = (_Float16)a; h.y = (_Float16)b; return h;
#endif
}
static __device__ __forceinline__ unsigned pku(float a, float b) {
    return __builtin_bit_cast(unsigned, pk(a, b));
}

// Each block = (batch, 512-px group, 8-slice d-chunk); 256 thr, 2 px/thread.
// x loaded global->register directly (coalesced float2 per channel) with
// depth-1 prefetch; weights live in LDS, read as wave-uniform broadcasts.
// NO __syncthreads in the main loop — latency hidden by TLP.
// launch_bounds (256,2): VGPR cap 128 — R14's (256,4) capped at 64 and spilled.
__global__ __launch_bounds__(256, 2)
void mlp_kernel(const float* __restrict__ x,
                const float* __restrict__ w0, const float* __restrict__ g0,
                const float* __restrict__ b0, const float* __restrict__ m0,
                const float* __restrict__ v0,
                const float* __restrict__ w1, const float* __restrict__ g1,
                const float* __restrict__ b1, const float* __restrict__ m1,
                const float* __restrict__ v1,
                const float* __restrict__ w2,
                float* __restrict__ ws)
{
    // LDS: only the f16-packed folded weights (~0.7 KB).
    __shared__ __align__(16) unsigned lw0u[64];   // [o][i] o<16 i<4 (ch pairs)
    __shared__ __align__(16) float    lb0[16];
    __shared__ __align__(16) unsigned lw1u[64];   // [j][i] j<8 i<8 (h0 pairs)
    __shared__ __align__(16) float    lb1[8];
    __shared__ __align__(16) unsigned lw2u[4];

    const int tid = threadIdx.x;

    // Task decode: 960 = 4 batches x 40 groups x 6 chunks.
    const int t     = blockIdx.x;
    const int batch = t / (NGRP * NCHNK);
    const int r     = t - batch * (NGRP * NCHNK);
    const int grp   = r / NCHNK;
    const int chunk = r - grp * NCHNK;

    // ---- per-block BN fold into LDS (f16 pairs) ----
    if (tid < 16) {
        float sc = g0[tid] * rsqrtf(v0[tid] + EPS);
#pragma unroll
        for (int i = 0; i < 4; ++i)
            lw0u[tid * 4 + i] = pku(w0[tid * 8 + 2 * i] * sc, w0[tid * 8 + 2 * i + 1] * sc);
        lb0[tid] = b0[tid] - m0[tid] * sc;
    } else if (tid < 24) {
        int j = tid - 16;
        float sc = g1[j] * rsqrtf(v1[j] + EPS);
#pragma unroll
        for (int i = 0; i < 8; ++i)
            lw1u[j * 8 + i] = pku(w1[j * 16 + 2 * i] * sc, w1[j * 16 + 2 * i + 1] * sc);
        lb1[j] = b1[j] - m1[j] * sc;
    } else if (tid == 24) {
#pragma unroll
        for (int i = 0; i < 4; ++i) lw2u[i] = pku(w2[2 * i], w2[2 * i + 1]);
    }
    __syncthreads();   // the ONLY barrier: weights ready

    // Pixel-pair base for this thread within its d-chunk.
    const float* xp = x + (size_t)batch * CDHW + (size_t)(chunk * DSTEP) * HW
                        + grp * GPX + tid * 2;

    float maxv0 = -1e30f, maxv1 = -1e30f;

    // Depth-1 register prefetch: cur holds slice dd, nxt is loading dd+1.
    float2 cur[8], nxt[8];
#pragma unroll
    for (int c = 0; c < 8; ++c) cur[c] = *(const float2*)(xp + (size_t)c * DHW);

    for (int dd = 0; dd < DSTEP; ++dd) {
        if (dd + 1 < DSTEP) {
            const float* xq = xp + (size_t)(dd + 1) * HW;
#pragma unroll
            for (int c = 0; c < 8; ++c) nxt[c] = *(const float2*)(xq + (size_t)c * DHW);
        }

        // ---- pack 2 px x 8 ch to f16 pairs ----
        half2v xh0[4], xh1[4];
#pragma unroll
        for (int i = 0; i < 4; ++i) {
            xh0[i] = pk(cur[2 * i].x, cur[2 * i + 1].x);
            xh1[i] = pk(cur[2 * i].y, cur[2 * i + 1].y);
        }

        // ---- layer 0: 8 -> 16, relu, pack pairs (both px) ----
        unsigned hh0[8], hh1[8];
#pragma unroll
        for (int op = 0; op < 8; ++op) {
            uint4 wA = *(const uint4*)&lw0u[(2 * op) * 4];
            uint4 wB = *(const uint4*)&lw0u[(2 * op + 1) * 4];
            float bA = lb0[2 * op], bB = lb0[2 * op + 1];
            float a0 = bA, c0 = bB, a1 = bA, c1 = bB;
            a0 = dot2u(xh0[0], wA.x, a0); a0 = dot2u(xh0[1], wA.y, a0);
            a0 = dot2u(xh0[2], wA.z, a0); a0 = dot2u(xh0[3], wA.w, a0);
            c0 = dot2u(xh0[0], wB.x, c0); c0 = dot2u(xh0[1], wB.y, c0);
            c0 = dot2u(xh0[2], wB.z, c0); c0 = dot2u(xh0[3], wB.w, c0);
            a1 = dot2u(xh1[0], wA.x, a1); a1 = dot2u(xh1[1], wA.y, a1);
            a1 = dot2u(xh1[2], wA.z, a1); a1 = dot2u(xh1[3], wA.w, a1);
            c1 = dot2u(xh1[0], wB.x, c1); c1 = dot2u(xh1[1], wB.y, c1);
            c1 = dot2u(xh1[2], wB.z, c1); c1 = dot2u(xh1[3], wB.w, c1);
            hh0[op] = pku(fmaxf(a0, 0.f), fmaxf(c0, 0.f));
            hh1[op] = pku(fmaxf(a1, 0.f), fmaxf(c1, 0.f));
        }

        // ---- layer 1: 16 -> 8, relu, pack pairs (explicit per-pixel) ----
        unsigned hq0[4], hq1[4];
#define L1PX(HH, HQ)                                                              \
        {                                                                         \
            float a = bA, b = bB;                                                 \
            a = dot2u(__builtin_bit_cast(half2v, HH[0]), wA0.x, a);               \
            a = dot2u(__builtin_bit_cast(half2v, HH[1]), wA0.y, a);               \
            a = dot2u(__builtin_bit_cast(half2v, HH[2]), wA0.z, a);               \
            a = dot2u(__builtin_bit_cast(half2v, HH[3]), wA0.w, a);               \
            a = dot2u(__builtin_bit_cast(half2v, HH[4]), wA1.x, a);               \
            a = dot2u(__builtin_bit_cast(half2v, HH[5]), wA1.y, a);               \
            a = dot2u(__builtin_bit_cast(half2v, HH[6]), wA1.z, a);               \
            a = dot2u(__builtin_bit_cast(half2v, HH[7]), wA1.w, a);               \
            b = dot2u(__builtin_bit_cast(half2v, HH[0]), wB0.x, b);               \
            b = dot2u(__builtin_bit_cast(half2v, HH[1]), wB0.y, b);               \
            b = dot2u(__builtin_bit_cast(half2v, HH[2]), wB0.z, b);               \
            b = dot2u(__builtin_bit_cast(half2v, HH[3]), wB0.w, b);               \
            b = dot2u(__builtin_bit_cast(half2v, HH[4]), wB1.x, b);               \
            b = dot2u(__builtin_bit_cast(half2v, HH[5]), wB1.y, b);               \
            b = dot2u(__builtin_bit_cast(half2v, HH[6]), wB1.z, b);               \
            b = dot2u(__builtin_bit_cast(half2v, HH[7]), wB1.w, b);               \
            HQ[jp] = pku(fmaxf(a, 0.f), fmaxf(b, 0.f));                           \
        }
#pragma unroll
        for (int jp = 0; jp < 4; ++jp) {
            uint4 wA0 = *(const uint4*)&lw1u[(2 * jp) * 8];
            uint4 wA1 = *(const uint4*)&lw1u[(2 * jp) * 8 + 4];
            uint4 wB0 = *(const uint4*)&lw1u[(2 * jp + 1) * 8];
            uint4 wB1 = *(const uint4*)&lw1u[(2 * jp + 1) * 8 + 4];
            float bA = lb1[2 * jp], bB = lb1[2 * jp + 1];
            L1PX(hh0, hq0)
            L1PX(hh1, hq1)
        }
#undef L1PX

        // ---- layer 2: 8 -> 1 (bias2 deferred), running max ----
        {
            uint4 w2v = *(const uint4*)&lw2u[0];
            float a0 = 0.f, a1 = 0.f;
            a0 = dot2u(__builtin_bit_cast(half2v, hq0[0]), w2v.x, a0);
            a0 = dot2u(__builtin_bit_cast(half2v, hq0[1]), w2v.y, a0);
            a0 = dot2u(__builtin_bit_cast(half2v, hq0[2]), w2v.z, a0);
            a0 = dot2u(__builtin_bit_cast(half2v, hq0[3]), w2v.w, a0);
            a1 = dot2u(__builtin_bit_cast(half2v, hq1[0]), w2v.x, a1);
            a1 = dot2u(__builtin_bit_cast(half2v, hq1[1]), w2v.y, a1);
            a1 = dot2u(__builtin_bit_cast(half2v, hq1[2]), w2v.z, a1);
            a1 = dot2u(__builtin_bit_cast(half2v, hq1[3]), w2v.w, a1);
            maxv0 = fmaxf(maxv0, a0);
            maxv1 = fmaxf(maxv1, a1);
        }

#pragma unroll
        for (int c = 0; c < 8; ++c) cur[c] = nxt[c];
    }

    // Plain store of this chunk's partial max.
    float2 st; st.x = maxv0; st.y = maxv1;
    *(float2*)&ws[(size_t)chunk * NPIX + (size_t)batch * HW + grp * GPX + tid * 2] = st;
}

// Reduce 6 chunk-partials, add bias2, sigmoid (monotone => commutes with max).
__global__ __launch_bounds__(256)
void finish_kernel(const float* __restrict__ ws, const float* __restrict__ bias2,
                   float* __restrict__ out)
{
    int i = blockIdx.x * 256 + threadIdx.x;
    float m = ws[i];
#pragma unroll
    for (int c = 1; c < NCHNK; ++c) m = fmaxf(m, ws[(size_t)c * NPIX + i]);
    m += bias2[0];
    out[i] = 1.0f / (1.0f + __expf(-m));
}

extern "C" void kernel_launch(void* const* d_in, const int* in_sizes, int n_in,
                              void* d_out, int out_size, void* d_ws, size_t ws_size,
                              hipStream_t stream) {
    const float* x1 = (const float*)d_in[0];
    float* ws = (float*)d_ws;   // needs 6 * 81920 * 4 = 2 MB

    mlp_kernel<<<NBLK, 256, 0, stream>>>(
        x1,
        (const float*)d_in[1], (const float*)d_in[2], (const float*)d_in[3],
        (const float*)d_in[4], (const float*)d_in[5],
        (const float*)d_in[6], (const float*)d_in[7], (const float*)d_in[8],
        (const float*)d_in[9], (const float*)d_in[10],
        (const float*)d_in[11],
        ws);
    finish_kernel<<<NPIX / 256, 256, 0, stream>>>(ws, (const float*)d_in[12],
                                                  (float*)d_out);
}

// Round 16
// 33.797 us; speedup vs baseline: 3.8561x; 1.0568x over previous
//
#include <hip/hip_runtime.h>

// Geometry (from reference): B=4, C=8, D=48, H=128, W=160
#define HW    20480      // H*W
#define DHW   983040     // D*H*W (channel stride, floats)
#define CDHW  7864320    // C*D*H*W (batch stride, floats)
#define NPIX  81920      // B*H*W
#define GPX   512        // pixels per block (256 thr x 2 px)
#define NGRP  40         // pixel groups per batch (HW / GPX)
#define DSTEP 6          // d-slices per chunk
#define NCHNK 8          // 48 / DSTEP
#define NBLK  (4 * NGRP * NCHNK)   // 1280 blocks = exactly 5 per CU
#define EPS   1e-5f

typedef _Float16 half2v __attribute__((ext_vector_type(2)));

static __device__ __forceinline__ float dot2u(half2v a, unsigned wb, float c) {
#if __has_builtin(__builtin_amdgcn_fdot2)
    return __builtin_amdgcn_fdot2(a, __builtin_bit_cast(half2v, wb), c, false);
#else
    half2v b = __builtin_bit_cast(half2v, wb);
    return fmaf((float)a.x, (float)b.x, fmaf((float)a.y, (float)b.y, c));
#endif
}
static __device__ __forceinline__ half2v pk(float a, float b) {
#if __has_builtin(__builtin_amdgcn_cvt_pkrtz)
    return __builtin_bit_cast(half2v, __builtin_amdgcn_cvt_pkrtz(a, b));
#else
    half2v h; h.x = (_Float16)a; h.y = (_Float16)b; return h;
#endif
}
static __device__ __forceinline__ unsigned pku(float a, float b) {
    return __builtin_bit_cast(unsigned, pk(a, b));
}

// Each block = (batch, 512-px group, 6-slice d-chunk); 256 thr, 2 px/thread.
// x loaded global->register directly (coalesced float2 per channel) with
// depth-1 prefetch; weights live in LDS, read as wave-uniform broadcasts.
// NO __syncthreads in the main loop — latency hidden by TLP.
// launch_bounds (256,2): VGPR cap 128 (R14's (256,4) capped at 64 -> spill storm).
__global__ __launch_bounds__(256, 2)
void mlp_kernel(const float* __restrict__ x,
                const float* __restrict__ w0, const float* __restrict__ g0,
                const float* __restrict__ b0, const float* __restrict__ m0,
                const float* __restrict__ v0,
                const float* __restrict__ w1, const float* __restrict__ g1,
                const float* __restrict__ b1, const float* __restrict__ m1,
                const float* __restrict__ v1,
                const float* __restrict__ w2,
                float* __restrict__ ws)
{
    // LDS: only the f16-packed folded weights (~0.7 KB).
    __shared__ __align__(16) unsigned lw0u[64];   // [o][i] o<16 i<4 (ch pairs)
    __shared__ __align__(16) float    lb0[16];
    __shared__ __align__(16) unsigned lw1u[64];   // [j][i] j<8 i<8 (h0 pairs)
    __shared__ __align__(16) float    lb1[8];
    __shared__ __align__(16) unsigned lw2u[4];

    const int tid = threadIdx.x;

    // Task decode: 1280 = 4 batches x 40 groups x 8 chunks.
    const int t     = blockIdx.x;
    const int batch = t / (NGRP * NCHNK);
    const int r     = t - batch * (NGRP * NCHNK);
    const int grp   = r / NCHNK;
    const int chunk = r - grp * NCHNK;

    // ---- per-block BN fold into LDS (f16 pairs) ----
    if (tid < 16) {
        float sc = g0[tid] * rsqrtf(v0[tid] + EPS);
#pragma unroll
        for (int i = 0; i < 4; ++i)
            lw0u[tid * 4 + i] = pku(w0[tid * 8 + 2 * i] * sc, w0[tid * 8 + 2 * i + 1] * sc);
        lb0[tid] = b0[tid] - m0[tid] * sc;
    } else if (tid < 24) {
        int j = tid - 16;
        float sc = g1[j] * rsqrtf(v1[j] + EPS);
#pragma unroll
        for (int i = 0; i < 8; ++i)
            lw1u[j * 8 + i] = pku(w1[j * 16 + 2 * i] * sc, w1[j * 16 + 2 * i + 1] * sc);
        lb1[j] = b1[j] - m1[j] * sc;
    } else if (tid == 24) {
#pragma unroll
        for (int i = 0; i < 4; ++i) lw2u[i] = pku(w2[2 * i], w2[2 * i + 1]);
    }
    __syncthreads();   // the ONLY barrier: weights ready

    // Pixel-pair base for this thread within its d-chunk.
    const float* xp = x + (size_t)batch * CDHW + (size_t)(chunk * DSTEP) * HW
                        + grp * GPX + tid * 2;

    float maxv0 = -1e30f, maxv1 = -1e30f;

    // Depth-1 register prefetch: cur holds slice dd, nxt is loading dd+1.
    float2 cur[8], nxt[8];
#pragma unroll
    for (int c = 0; c < 8; ++c) cur[c] = *(const float2*)(xp + (size_t)c * DHW);

    for (int dd = 0; dd < DSTEP; ++dd) {
        if (dd + 1 < DSTEP) {
            const float* xq = xp + (size_t)(dd + 1) * HW;
#pragma unroll
            for (int c = 0; c < 8; ++c) nxt[c] = *(const float2*)(xq + (size_t)c * DHW);
        }

        // ---- pack 2 px x 8 ch to f16 pairs ----
        half2v xh0[4], xh1[4];
#pragma unroll
        for (int i = 0; i < 4; ++i) {
            xh0[i] = pk(cur[2 * i].x, cur[2 * i + 1].x);
            xh1[i] = pk(cur[2 * i].y, cur[2 * i + 1].y);
        }

        // ---- layer 0: 8 -> 16, relu, pack pairs (both px) ----
        unsigned hh0[8], hh1[8];
#pragma unroll
        for (int op = 0; op < 8; ++op) {
            uint4 wA = *(const uint4*)&lw0u[(2 * op) * 4];
            uint4 wB = *(const uint4*)&lw0u[(2 * op + 1) * 4];
            float bA = lb0[2 * op], bB = lb0[2 * op + 1];
            float a0 = bA, c0 = bB, a1 = bA, c1 = bB;
            a0 = dot2u(xh0[0], wA.x, a0); a0 = dot2u(xh0[1], wA.y, a0);
            a0 = dot2u(xh0[2], wA.z, a0); a0 = dot2u(xh0[3], wA.w, a0);
            c0 = dot2u(xh0[0], wB.x, c0); c0 = dot2u(xh0[1], wB.y, c0);
            c0 = dot2u(xh0[2], wB.z, c0); c0 = dot2u(xh0[3], wB.w, c0);
            a1 = dot2u(xh1[0], wA.x, a1); a1 = dot2u(xh1[1], wA.y, a1);
            a1 = dot2u(xh1[2], wA.z, a1); a1 = dot2u(xh1[3], wA.w, a1);
            c1 = dot2u(xh1[0], wB.x, c1); c1 = dot2u(xh1[1], wB.y, c1);
            c1 = dot2u(xh1[2], wB.z, c1); c1 = dot2u(xh1[3], wB.w, c1);
            hh0[op] = pku(fmaxf(a0, 0.f), fmaxf(c0, 0.f));
            hh1[op] = pku(fmaxf(a1, 0.f), fmaxf(c1, 0.f));
        }

        // ---- layer 1: 16 -> 8, relu, pack pairs (explicit per-pixel) ----
        unsigned hq0[4], hq1[4];
#define L1PX(HH, HQ)                                                              \
        {                                                                         \
            float a = bA, b = bB;                                                 \
            a = dot2u(__builtin_bit_cast(half2v, HH[0]), wA0.x, a);               \
            a = dot2u(__builtin_bit_cast(half2v, HH[1]), wA0.y, a);               \
            a = dot2u(__builtin_bit_cast(half2v, HH[2]), wA0.z, a);               \
            a = dot2u(__builtin_bit_cast(half2v, HH[3]), wA0.w, a);               \
            a = dot2u(__builtin_bit_cast(half2v, HH[4]), wA1.x, a);               \
            a = dot2u(__builtin_bit_cast(half2v, HH[5]), wA1.y, a);               \
            a = dot2u(__builtin_bit_cast(half2v, HH[6]), wA1.z, a);               \
            a = dot2u(__builtin_bit_cast(half2v, HH[7]), wA1.w, a);               \
            b = dot2u(__builtin_bit_cast(half2v, HH[0]), wB0.x, b);               \
            b = dot2u(__builtin_bit_cast(half2v, HH[1]), wB0.y, b);               \
            b = dot2u(__builtin_bit_cast(half2v, HH[2]), wB0.z, b);               \
            b = dot2u(__builtin_bit_cast(half2v, HH[3]), wB0.w, b);               \
            b = dot2u(__builtin_bit_cast(half2v, HH[4]), wB1.x, b);               \
            b = dot2u(__builtin_bit_cast(half2v, HH[5]), wB1.y, b);               \
            b = dot2u(__builtin_bit_cast(half2v, HH[6]), wB1.z, b);               \
            b = dot2u(__builtin_bit_cast(half2v, HH[7]), wB1.w, b);               \
            HQ[jp] = pku(fmaxf(a, 0.f), fmaxf(b, 0.f));                           \
        }
#pragma unroll
        for (int jp = 0; jp < 4; ++jp) {
            uint4 wA0 = *(const uint4*)&lw1u[(2 * jp) * 8];
            uint4 wA1 = *(const uint4*)&lw1u[(2 * jp) * 8 + 4];
            uint4 wB0 = *(const uint4*)&lw1u[(2 * jp + 1) * 8];
            uint4 wB1 = *(const uint4*)&lw1u[(2 * jp + 1) * 8 + 4];
            float bA = lb1[2 * jp], bB = lb1[2 * jp + 1];
            L1PX(hh0, hq0)
            L1PX(hh1, hq1)
        }
#undef L1PX

        // ---- layer 2: 8 -> 1 (bias2 deferred), running max ----
        {
            uint4 w2v = *(const uint4*)&lw2u[0];
            float a0 = 0.f, a1 = 0.f;
            a0 = dot2u(__builtin_bit_cast(half2v, hq0[0]), w2v.x, a0);
            a0 = dot2u(__builtin_bit_cast(half2v, hq0[1]), w2v.y, a0);
            a0 = dot2u(__builtin_bit_cast(half2v, hq0[2]), w2v.z, a0);
            a0 = dot2u(__builtin_bit_cast(half2v, hq0[3]), w2v.w, a0);
            a1 = dot2u(__builtin_bit_cast(half2v, hq1[0]), w2v.x, a1);
            a1 = dot2u(__builtin_bit_cast(half2v, hq1[1]), w2v.y, a1);
            a1 = dot2u(__builtin_bit_cast(half2v, hq1[2]), w2v.z, a1);
            a1 = dot2u(__builtin_bit_cast(half2v, hq1[3]), w2v.w, a1);
            maxv0 = fmaxf(maxv0, a0);
            maxv1 = fmaxf(maxv1, a1);
        }

#pragma unroll
        for (int c = 0; c < 8; ++c) cur[c] = nxt[c];
    }

    // Plain store of this chunk's partial max.
    float2 st; st.x = maxv0; st.y = maxv1;
    *(float2*)&ws[(size_t)chunk * NPIX + (size_t)batch * HW + grp * GPX + tid * 2] = st;
}

// Reduce 8 chunk-partials, add bias2, sigmoid (monotone => commutes with max).
__global__ __launch_bounds__(256)
void finish_kernel(const float* __restrict__ ws, const float* __restrict__ bias2,
                   float* __restrict__ out)
{
    int i = blockIdx.x * 256 + threadIdx.x;
    float m = ws[i];
#pragma unroll
    for (int c = 1; c < NCHNK; ++c) m = fmaxf(m, ws[(size_t)c * NPIX + i]);
    m += bias2[0];
    out[i] = 1.0f / (1.0f + __expf(-m));
}

extern "C" void kernel_launch(void* const* d_in, const int* in_sizes, int n_in,
                              void* d_out, int out_size, void* d_ws, size_t ws_size,
                              hipStream_t stream) {
    const float* x1 = (const float*)d_in[0];
    float* ws = (float*)d_ws;   // needs 8 * 81920 * 4 = 2.6 MB

    mlp_kernel<<<NBLK, 256, 0, stream>>>(
        x1,
        (const float*)d_in[1], (const float*)d_in[2], (const float*)d_in[3],
        (const float*)d_in[4], (const float*)d_in[5],
        (const float*)d_in[6], (const float*)d_in[7], (const float*)d_in[8],
        (const float*)d_in[9], (const float*)d_in[10],
        (const float*)d_in[11],
        ws);
    finish_kernel<<<NPIX / 256, 256, 0, stream>>>(ws, (const float*)d_in[12],
                                                  (float*)d_out);
}